// Round 10
// baseline (71.106 us; speedup 1.0000x reference)
//
#include <hip/hip_runtime.h>

// Sinkhorn (eps=0.2, 50 iters), 64x64 images, b=64. Separable banded Gibbs:
// K = G (x) G, G[i,k]=exp(-5(i-k)^2), radius 2 in fp32.
//
// R10: R9's LDS-free DPP data path + stall-overlap + fused reduction.
//  - Lane = image row (64 lanes). 8 waves/image, wave w owns cols 8w..8w+7.
//    With 2 waves/SIMD, one wave's VALU issue fills the other's barrier/LDS/
//    dep-latency stalls (R9 at 1 wave/SIMD exposed ~60% of each iter as stall:
//    VALUBusy 14.5%, 2770 cyc/iter vs ~1100 cyc of issue).
//  - Vertical conv: DPP wave_shr:1 (0x138) / wave_shl:1 (0x130), bound_ctrl
//    0-fill = exact zero-padded edges (HW-verified bitwise in R9, absmax 0).
//  - Horizontal conv: registers; per-apply edge-col exchange via LDS
//    (4 ds_write_b32 + 4 ds_read_b32 per wave, lane-consecutive = conflict-
//    free), one __syncthreads per apply; two alternating buffers make
//    cross-apply WAR safe; guard slots 0/9 stay zero = horizontal zero-pad.
//  - Reduction fused: per-block partial -> __threadfence -> atomicAdd counter;
//    last block sums the 64 partials in fixed order (deterministic) -> out.
//    Kills the 2nd kernel launch (~3-4us). Counter zeroed via hipMemsetAsync.

template<int CTRL>
__device__ __forceinline__ float dppf(float v) {
    return __builtin_bit_cast(float,
        __builtin_amdgcn_update_dpp(0, __builtin_bit_cast(int, v),
                                    CTRL, 0xF, 0xF, true));
}
#define SHR1(v) dppf<0x138>(v)   // out[r] = in[r-1], row 0 gets 0
#define SHL1(v) dppf<0x130>(v)   // out[r] = in[r+1], row 63 gets 0

__device__ __forceinline__ float frcp_nr(float d) {
    float r = __builtin_amdgcn_rcpf(d);
    return r * fmaf(-d, r, 2.0f);   // 1 Newton step: ~1 ulp
}

// One K-apply on 8 columns: vertical 5-tap (DPP) -> edge exchange (LDS) ->
// horizontal 5-tap (regs). VC/HC: include center tap (G) or not (G2).
template<bool VC, bool HC>
__device__ __forceinline__ void kapply(const float* __restrict__ s,
                                       float* __restrict__ o,
                                       float* __restrict__ ebw,
                                       const float* __restrict__ ebl,
                                       const float* __restrict__ ebr,
                                       float vt1, float vt2,
                                       float ht1, float ht2)
{
    float tv[8];
#pragma unroll
    for (int c = 0; c < 8; ++c) {
        float m1 = SHR1(s[c]), p1 = SHL1(s[c]);
        float m2 = SHR1(m1),   p2 = SHL1(p1);
        float s1 = m1 + p1,    s2 = m2 + p2;
        tv[c] = VC ? fmaf(vt2, s2, fmaf(vt1, s1, s[c]))
                   : fmaf(vt2, s2, vt1 * s1);
    }
    // publish edge cols: slots e=0,1,2,3 <-> own cols 0,1,6,7
    ebw[0]   = tv[0];
    ebw[64]  = tv[1];
    ebw[128] = tv[6];
    ebw[192] = tv[7];
    __syncthreads();
    float hl2 = ebl[128], hl1 = ebl[192];   // left neighbor cols 8w-2, 8w-1
    float hr1 = ebr[0],   hr2 = ebr[64];    // right neighbor cols 8w+8, 8w+9
    float W[12];
    W[0] = hl2; W[1] = hl1;
#pragma unroll
    for (int c = 0; c < 8; ++c) W[c + 2] = tv[c];
    W[10] = hr1; W[11] = hr2;
#pragma unroll
    for (int c = 0; c < 8; ++c) {
        float s1 = W[c + 1] + W[c + 3], s2 = W[c] + W[c + 4];
        o[c] = HC ? fmaf(ht2, s2, fmaf(ht1, s1, W[c + 2]))
                  : fmaf(ht2, s2, ht1 * s1);
    }
}

extern "C" __global__ void __launch_bounds__(512)
sinkhorn_kernel(const float* __restrict__ x, const float* __restrict__ y,
                const float* __restrict__ cost, const float* __restrict__ kern,
                float* __restrict__ partials, unsigned* __restrict__ cnt,
                float* __restrict__ out)
{
    // 2 halo buffers: [10 w-slots][4 e-slots][64 lanes]; slots 0 and 9 are
    // permanent zero guards (horizontal zero-padding of the image).
    __shared__ float EB[2][2560];
    __shared__ float wsum[8];

    const int t = threadIdx.x;
    const int r = t & 63;        // lane = row
    const int w = t >> 6;        // wave = col group (cols 8w..8w+7)
    const int b = blockIdx.x;

    // zero both buffers once (guards stay zero forever)
    for (int i = t; i < 5120; i += 512) ((float*)EB)[i] = 0.0f;

    const float g1 = kern[(size_t)64  * 4096];        // e^-5
    const float g2 = kern[(size_t)128 * 4096];        // e^-20
    const float q1 = cost[(size_t)64  * 4096] * g1;   // 1*e^-5
    const float q2 = cost[(size_t)128 * 4096] * g2;   // 4*e^-20

    float* const ebw0 = &EB[0][(w + 1) * 256 + r];
    const float* const ebl0 = &EB[0][w * 256 + r];
    const float* const ebr0 = &EB[0][(w + 2) * 256 + r];
    float* const ebw1 = &EB[1][(w + 1) * 256 + r];
    const float* const ebl1 = &EB[1][w * 256 + r];
    const float* const ebr1 = &EB[1][(w + 2) * 256 + r];

    // marginals x[b][r][8w+c], y[b][r][8w+c] in registers (float4 loads)
    float xv[8], yv[8];
    {
        const float* xb = x + (size_t)b * 4096 + 64 * r + 8 * w;
        const float* yb = y + (size_t)b * 4096 + 64 * r + 8 * w;
        float4 f;
        f = *(const float4*)(xb);     xv[0]=f.x; xv[1]=f.y; xv[2]=f.z; xv[3]=f.w;
        f = *(const float4*)(xb + 4); xv[4]=f.x; xv[5]=f.y; xv[6]=f.z; xv[7]=f.w;
        f = *(const float4*)(yb);     yv[0]=f.x; yv[1]=f.y; yv[2]=f.z; yv[3]=f.w;
        f = *(const float4*)(yb + 4); yv[4]=f.x; yv[5]=f.y; yv[6]=f.z; yv[7]=f.w;
    }

    float V[8], U[8], tb[8];
#pragma unroll
    for (int c = 0; c < 8; ++c) V[c] = 1.0f / 4096.0f;

#pragma unroll 1
    for (int it = 0; it < 50; ++it) {
        // U = x / (G*V*G + 1e-8)
        kapply<true, true>(V, tb, ebw0, ebl0, ebr0, g1, g2, g1, g2);
#pragma unroll
        for (int c = 0; c < 8; ++c) U[c] = xv[c] * frcp_nr(tb[c] + 1e-8f);
        // V = y / (G*U*G + 1e-8)
        kapply<true, true>(U, tb, ebw1, ebl1, ebr1, g1, g2, g1, g2);
#pragma unroll
        for (int c = 0; c < 8; ++c) V[c] = yv[c] * frcp_nr(tb[c] + 1e-8f);
    }

    // distance: sum U o ((G2*V)*G) + sum U o ((G*V)*G2)
    float acc = 0.0f;
    kapply<false, true>(V, tb, ebw0, ebl0, ebr0, q1, q2, g1, g2);
#pragma unroll
    for (int c = 0; c < 8; ++c) acc = fmaf(U[c], tb[c], acc);
    kapply<true, false>(V, tb, ebw1, ebl1, ebr1, g1, g2, q1, q2);
#pragma unroll
    for (int c = 0; c < 8; ++c) acc = fmaf(U[c], tb[c], acc);

    // per-block reduction: wave shfl tree, then fixed-order 8-way sum
#pragma unroll
    for (int off = 32; off > 0; off >>= 1)
        acc += __shfl_down(acc, off, 64);
    if (r == 0) wsum[w] = acc;
    __syncthreads();
    if (t == 0) {
        float s = ((wsum[0] + wsum[1]) + (wsum[2] + wsum[3]))
                + ((wsum[4] + wsum[5]) + (wsum[6] + wsum[7]));
        partials[b] = s;
        __threadfence();                       // partials visible device-wide
        unsigned old = atomicAdd(cnt, 1u);     // device-scope by default
        if (old == gridDim.x - 1) {            // last block finalizes
            __threadfence();
            float tot = 0.0f;
            volatile const float* vp = partials;
            for (int i = 0; i < 64; ++i) tot += vp[i];   // fixed order
            out[0] = tot;
        }
    }
}

extern "C" void kernel_launch(void* const* d_in, const int* in_sizes, int n_in,
                              void* d_out, int out_size, void* d_ws, size_t ws_size,
                              hipStream_t stream)
{
    const float* x    = (const float*)d_in[0];
    const float* y    = (const float*)d_in[1];
    const float* cost = (const float*)d_in[2];
    const float* kern = (const float*)d_in[3];
    float* partials   = (float*)d_ws;                       // 64 floats
    unsigned* cnt     = (unsigned*)((char*)d_ws + 256);     // completion counter

    hipMemsetAsync(cnt, 0, sizeof(unsigned), stream);       // capture-safe
    sinkhorn_kernel<<<64, 512, 0, stream>>>(x, y, cost, kern,
                                            partials, cnt, (float*)d_out);
}